// Round 7
// baseline (230.466 us; speedup 1.0000x reference)
//
#include <hip/hip_runtime.h>
#include <hip/hip_bf16.h>

typedef unsigned int u32;
typedef unsigned short u16;

#define DIM 128
#define LWS 136    // LDS row stride in u16 (128 + 8 pad = 272 B, 16B-aligned)
#define CHUNK 2048 // radix sort: keys per block

typedef __bf16 bfrag __attribute__((ext_vector_type(8)));   // MFMA A/B frag (4 VGPRs)
typedef float  facc  __attribute__((ext_vector_type(4)));   // MFMA C/D frag

__device__ __forceinline__ float2 bfpair(u32 u) {
    union { u32 i; float f; } lo, hi;
    lo.i = (u & 0xFFFFu) << 16;
    hi.i = u & 0xFFFF0000u;
    return make_float2(lo.f, hi.f);
}
__device__ __forceinline__ float bf1(u16 h) {
    union { u32 i; float f; } a; a.i = ((u32)h) << 16; return a.f;
}
__device__ __forceinline__ u16 f2bf(float f) {
    __hip_bfloat16 h = __float2bfloat16(f);   // RNE
    return *reinterpret_cast<u16*>(&h);
}
__device__ __forceinline__ u32 packbf(float x, float y) {
    return (u32)f2bf(x) | ((u32)f2bf(y) << 16);
}

template<bool BF16>
__device__ __forceinline__ float ldf(const void* p, int i) {
    if constexpr (BF16) return bf1(((const u16*)p)[i]);
    else                return ((const float*)p)[i];
}

// load an 8-element bf16 fragment from row-major [*,128] matrix (proven R2-R5)
template<bool BF16>
__device__ __forceinline__ bfrag ldfrag(const void* base, int row, int elt) {
    if constexpr (BF16) {
        const uint4* p = (const uint4*)((const u16*)base + (size_t)row * DIM + elt);
        return __builtin_bit_cast(bfrag, *p);
    } else {
        const float4* p = (const float4*)((const float*)base + (size_t)row * DIM + elt);
        float4 f0 = p[0], f1 = p[1];
        uint4 u = make_uint4(packbf(f0.x, f0.y), packbf(f0.z, f0.w),
                             packbf(f1.x, f1.y), packbf(f1.z, f1.w));
        return __builtin_bit_cast(bfrag, u);
    }
}

// ---------------------------------------------------------------------------
// Sniffer (R2-proven): flags[0]=1 if float tensors are bf16; flags[1]=1 if
// edge_index is int64 layout.
// ---------------------------------------------------------------------------
__global__ __launch_bounds__(64) void sniff_kernel(const u32* __restrict__ x0w,
                                                   const int* __restrict__ eiw,
                                                   int* __restrict__ flags) {
    int l = threadIdx.x;
    u32 w = x0w[l];
    u32 ef = (w >> 7) & 0xFF;                 // exponent of low halfword if bf16
    bool inr = (ef >= 99 && ef <= 141);
    unsigned long long m1 = __ballot(inr);
    bool zodd = (eiw[2 * l + 1] == 0);
    unsigned long long m2 = __ballot(zodd);
    if (l == 0) {
        flags[0] = (__popcll(m1) >= 48) ? 1 : 0;
        flags[1] = (__popcll(m2) >= 32) ? 1 : 0;
    }
}

// ---------------------------------------------------------------------------
// MFMA projection (R4-R8 proven standalone form). One block = 4 chunks of
// one matrix (grp). Produces xj (bf16), a1, a2.
// ---------------------------------------------------------------------------
template<bool BF16>
__global__ __launch_bounds__(256) void proj_kernel(
    const void* __restrict__ x0v,
    const void* __restrict__ W1v, const void* __restrict__ b1v,
    const void* __restrict__ W2v, const void* __restrict__ b2v,
    const void* __restrict__ a1wv, const void* __restrict__ a1bv,
    const void* __restrict__ a2wv, const void* __restrict__ a2bv,
    u16* __restrict__ xj, float* __restrict__ a1, float* __restrict__ a2,
    const int* __restrict__ flags, int n, int nchunk, int bpg)
{
    if ((flags[0] != 0) != BF16) return;      // wrong dtype: ghost launch
    __shared__ u16 lw[128 * LWS];             // ~34 KB

    const int t   = threadIdx.x;
    const int grp = blockIdx.x / bpg;         // 0: W1/a1, 1: W2/a2
    const int cb  = blockIdx.x % bpg;

    const void* Wv  = grp ? W2v  : W1v;
    const void* bv  = grp ? b2v  : b1v;
    const void* awv = grp ? a2wv : a1wv;
    const void* abv = grp ? a2bv : a1bv;
    float* aout     = grp ? a2   : a1;

    // stage W -> LDS as bf16 (16B chunks, padded rows)
    for (int j = t; j < 2048; j += 256) {
        int r = j >> 4, c = j & 15;
        uint4 u;
        if constexpr (BF16) {
            u = *(const uint4*)((const u16*)Wv + (size_t)r * DIM + c * 8);
        } else {
            const float4* p = (const float4*)((const float*)Wv + (size_t)r * DIM + c * 8);
            float4 f0 = p[0], f1 = p[1];
            u = make_uint4(packbf(f0.x, f0.y), packbf(f0.z, f0.w),
                           packbf(f1.x, f1.y), packbf(f1.z, f1.w));
        }
        *(uint4*)(lw + (size_t)r * LWS + c * 8) = u;
    }
    __syncthreads();

    const int wid = t >> 6, l = t & 63;
    const int chunk = cb * 4 + wid;
    if (chunk >= nchunk) return;
    const int r0 = chunk * 32;
    const int lr = l & 15;                    // A row / B col within tile
    const int q  = l >> 4;                    // quad -> k slice, C row group

    bfrag a[2][4];
    #pragma unroll
    for (int rt = 0; rt < 2; ++rt) {
        int row = min(r0 + rt * 16 + lr, n - 1);  // clamp (stores guarded)
        #pragma unroll
        for (int k = 0; k < 4; ++k)
            a[rt][k] = ldfrag<BF16>(x0v, row, k * 32 + q * 8);
    }

    facc acc[2][8];
    #pragma unroll
    for (int rt = 0; rt < 2; ++rt)
        #pragma unroll
        for (int ct = 0; ct < 8; ++ct)
            acc[rt][ct] = (facc){0.f, 0.f, 0.f, 0.f};

    #pragma unroll
    for (int ct = 0; ct < 8; ++ct) {
        bfrag bb[4];
        const u16* lrow = lw + (size_t)(ct * 16 + lr) * LWS;
        #pragma unroll
        for (int k = 0; k < 4; ++k)
            bb[k] = *(const bfrag*)(lrow + k * 32 + q * 8);
        #pragma unroll
        for (int rt = 0; rt < 2; ++rt)
            #pragma unroll
            for (int k = 0; k < 4; ++k)
                acc[rt][ct] = __builtin_amdgcn_mfma_f32_16x16x32_bf16(
                    a[rt][k], bb[k], acc[rt][ct], 0, 0, 0);
    }

    float s[2][4] = {{0.f,0.f,0.f,0.f},{0.f,0.f,0.f,0.f}};
    #pragma unroll
    for (int ct = 0; ct < 8; ++ct) {
        float bc  = ldf<BF16>(bv,  ct * 16 + lr);
        float awc = ldf<BF16>(awv, ct * 16 + lr);
        #pragma unroll
        for (int rt = 0; rt < 2; ++rt)
            #pragma unroll
            for (int reg = 0; reg < 4; ++reg) {
                float v = acc[rt][ct][reg] + bc;
                v = v >= 0.f ? v : 0.2f * v;          // LeakyReLU(0.2)
                int row = r0 + rt * 16 + q * 4 + reg;
                if (grp && row < n)
                    xj[(size_t)row * DIM + ct * 16 + lr] = f2bf(v);
                s[rt][reg] = fmaf(v, awc, s[rt][reg]);
            }
    }
    #pragma unroll
    for (int off = 1; off < 16; off <<= 1)
        #pragma unroll
        for (int rt = 0; rt < 2; ++rt)
            #pragma unroll
            for (int reg = 0; reg < 4; ++reg)
                s[rt][reg] += __shfl_xor(s[rt][reg], off);
    if (lr == 0) {
        float ab = ldf<BF16>(abv, 0);
        #pragma unroll
        for (int rt = 0; rt < 2; ++rt)
            #pragma unroll
            for (int reg = 0; reg < 4; ++reg) {
                int row = r0 + rt * 16 + q * 4 + reg;
                if (row < n) aout[row] = s[rt][reg] + ab;
            }
    }
}

// ---------------------------------------------------------------------------
// R11 radix sort (atomic-free CSR build). key = (src<<16)|dst, u32.
// Pass A: byte2 (src low 8), unordered-within-bucket ranking (cheap).
// Pass B: byte3 (src high 8), STABLE ranking via LDS count matrix.
// n < 65536 and dst < 65536 by problem shape (N=50000).
// ---------------------------------------------------------------------------

// count pass A: read ei, emit keys, histogram byte2. cnt layout [bin][block].
__global__ __launch_bounds__(256) void countA_kernel(
    const int* __restrict__ ei, u32* __restrict__ keys0,
    int* __restrict__ cnt, const int* __restrict__ flags, int ne, int nblk)
{
    __shared__ int h[256];
    const int b = blockIdx.x, t = threadIdx.x;
    h[t] = 0;
    __syncthreads();
    const bool i64 = flags[1] != 0;
    const int base = b * CHUNK;
    #pragma unroll
    for (int r = 0; r < CHUNK / 256; ++r) {
        int i = base + r * 256 + t;
        if (i < ne) {
            int src = i64 ? ei[2 * i] : ei[i];
            int dst = i64 ? ei[2 * (ne + i)] : ei[ne + i];
            u32 key = ((u32)src << 16) | (u32)dst;
            keys0[i] = key;
            atomicAdd(&h[(key >> 16) & 0xFF], 1);   // LDS atomic: no fabric
        }
    }
    __syncthreads();
    cnt[t * nblk + b] = h[t];
}

// count pass B: histogram byte3 of keys1.
__global__ __launch_bounds__(256) void countB_kernel(
    const u32* __restrict__ kin, int* __restrict__ cnt, int ne, int nblk)
{
    __shared__ int h[256];
    const int b = blockIdx.x, t = threadIdx.x;
    h[t] = 0;
    __syncthreads();
    const int base = b * CHUNK;
    #pragma unroll
    for (int r = 0; r < CHUNK / 256; ++r) {
        int i = base + r * 256 + t;
        if (i < ne) atomicAdd(&h[kin[i] >> 24], 1);
    }
    __syncthreads();
    cnt[t * nblk + b] = h[t];
}

// per-bin exclusive scan over blocks (one block per bin; nblk <= 512).
__global__ __launch_bounds__(256) void scan1_kernel(
    const int* __restrict__ cnt, int* __restrict__ off,
    int* __restrict__ tot, int nblk)
{
    __shared__ int v[512];
    const int d = blockIdx.x, t = threadIdx.x;
    int c0 = (t < nblk) ? cnt[d * nblk + t] : 0;
    int c1 = (t + 256 < nblk) ? cnt[d * nblk + t + 256] : 0;
    v[t] = c0; v[t + 256] = c1;
    __syncthreads();
    for (int s = 1; s < 512; s <<= 1) {
        int a0 = v[t],      b0 = (t >= s) ? v[t - s] : 0;
        int a1 = v[t + 256], b1 = (t + 256 >= s) ? v[t + 256 - s] : 0;
        __syncthreads();
        v[t] = a0 + b0; v[t + 256] = a1 + b1;
        __syncthreads();
    }
    if (t < nblk)       off[d * nblk + t]       = v[t] - c0;        // exclusive
    if (t + 256 < nblk) off[d * nblk + t + 256] = v[t + 256] - c1;
    if (t == 0) tot[d] = v[511];
}

// exclusive scan over 256 bin totals.
__global__ __launch_bounds__(256) void scan2_kernel(
    const int* __restrict__ tot, int* __restrict__ basev)
{
    __shared__ int v[256];
    const int t = threadIdx.x;
    int c = tot[t];
    v[t] = c;
    __syncthreads();
    for (int s = 1; s < 256; s <<= 1) {
        int a = v[t], b = (t >= s) ? v[t - s] : 0;
        __syncthreads();
        v[t] = a + b;
        __syncthreads();
    }
    basev[t] = v[t] - c;
}

// reorder pass A (byte2): within-bucket order free -> LDS-atomic ranks.
__global__ __launch_bounds__(256) void reorderA_kernel(
    const u32* __restrict__ kin, u32* __restrict__ kout,
    const int* __restrict__ off, const int* __restrict__ basev,
    int ne, int nblk)
{
    __shared__ u32 kk[CHUNK];
    __shared__ int boff[256];
    __shared__ int bcnt[256];
    const int b = blockIdx.x, t = threadIdx.x;
    const int base = b * CHUNK;
    const int cntk = min(CHUNK, ne - base);
    #pragma unroll
    for (int r = 0; r < CHUNK / 256; ++r) {
        int i = r * 256 + t;
        if (i < cntk) kk[i] = kin[base + i];
    }
    boff[t] = basev[t] + off[t * nblk + b];
    bcnt[t] = 0;
    __syncthreads();
    #pragma unroll
    for (int r = 0; r < CHUNK / 256; ++r) {
        int i = r * 256 + t;
        if (i < cntk) {
            u32 key = kk[i];
            int d = (key >> 16) & 0xFF;
            int rk = atomicAdd(&bcnt[d], 1);
            kout[boff[d] + rk] = key;
        }
    }
}

// reorder pass B (byte3): STABLE. 64 threads, 32 contiguous keys each.
// M[bin][thread] counts -> per-bin exclusive prefix over threads -> cell
// reused as running counter for intra-thread order. Rank is index-ordered.
__global__ __launch_bounds__(64) void reorderB_kernel(
    const u32* __restrict__ kin, u32* __restrict__ kout,
    const int* __restrict__ off, const int* __restrict__ basev,
    int ne, int nblk)
{
    __shared__ u16 M[256 * 65];   // [bin][thread], +1 pad column: 33.3 KB
    __shared__ u32 kk[CHUNK];     // 8 KB
    __shared__ int boff[256];     // 1 KB
    const int b = blockIdx.x, t = threadIdx.x;
    u32* M32 = (u32*)M;
    for (int j = t; j < 256 * 65 / 2; j += 64) M32[j] = 0;
    const int base = b * CHUNK;
    const int cntk = min(CHUNK, ne - base);
    for (int r = 0; r < CHUNK / 64; ++r) {        // coalesced stage
        int i = r * 64 + t;
        if (i < cntk) kk[i] = kin[base + i];
    }
    for (int d = t; d < 256; d += 64) boff[d] = basev[d] + off[d * nblk + b];
    __syncthreads();
    const int k0 = t * (CHUNK / 64);              // 32 contiguous keys
    for (int j = 0; j < CHUNK / 64; ++j) {
        int i = k0 + j;
        if (i < cntk) { int d = kk[i] >> 24; M[d * 65 + t] += 1; }  // cell (d,t) exclusive
    }
    __syncthreads();
    for (int rr = 0; rr < 4; ++rr) {              // per-bin prefix over threads
        int d = t + rr * 64;
        int run = 0, rb = d * 65;
        for (int j = 0; j < 64; ++j) {
            int c = M[rb + j]; M[rb + j] = (u16)run; run += c;
        }
    }
    __syncthreads();
    for (int j = 0; j < CHUNK / 64; ++j) {        // stable emit
        int i = k0 + j;
        if (i < cntk) {
            u32 key = kk[i];
            int d = key >> 24;
            int rk = M[d * 65 + t];
            M[d * 65 + t] = (u16)(rk + 1);
            kout[boff[d] + rk] = key;
        }
    }
}

// segment boundaries: ptr[s] = first sorted index with src >= s; ptr[n] = ne.
__global__ __launch_bounds__(256) void ptr_kernel(
    const u32* __restrict__ skeys, int* __restrict__ ptr, int ne, int n)
{
    int i = blockIdx.x * 256 + threadIdx.x;
    if (i >= ne) return;
    int s = (int)(skeys[i] >> 16);
    if (i == 0) {
        for (int j = 0; j <= s; ++j) ptr[j] = 0;
    } else {
        int sp = (int)(skeys[i - 1] >> 16);
        for (int j = sp + 1; j <= s; ++j) ptr[j] = i;
    }
    if (i == ne - 1) {
        for (int j = s + 1; j <= n; ++j) ptr[j] = ne;
    }
}

// ---------------------------------------------------------------------------
// Gather (R6 MLP-8 structure): one wave per src node, lane l = cols 2l,2l+1.
// R11: reads sorted u32 keys; att computed on the fly:
// att = sigmoid(a1[s] + a2[dst]) — a1[s] wave-uniform, a2[dst] broadcast
// (200 KB, L2-resident). Same f32 math as the old scatter.
// ---------------------------------------------------------------------------
template<bool BF16>
__global__ __launch_bounds__(256) void gather_kernel(
    const int* __restrict__ ptr, const u32* __restrict__ skeys,
    const float* __restrict__ a1, const float* __restrict__ a2,
    const u32* __restrict__ xjw, const void* __restrict__ x0v,
    void* __restrict__ outv, const int* __restrict__ flags, int n)
{
    if ((flags[0] != 0) != BF16) return;
    int s = blockIdx.x * 4 + (threadIdx.x >> 6);
    int l = threadIdx.x & 63;
    if (s >= n) return;

    float2 acc0, acc1;
    if constexpr (BF16) acc0 = bfpair(((const u32*)x0v)[(size_t)s * 64 + l]);
    else                acc0 = ((const float2*)x0v)[(size_t)s * 64 + l];
    acc1 = make_float2(0.f, 0.f);
    const float a1s = a1[s];

    int k = ptr[s], end = ptr[s + 1];

    while (k + 8 <= end) {
        u32 r[8];
        #pragma unroll
        for (int j = 0; j < 8; ++j) r[j] = skeys[k + j];
        u32 w[8]; float av[8];
        #pragma unroll
        for (int j = 0; j < 8; ++j) w[j] = xjw[(size_t)(r[j] & 0xFFFFu) * 64 + l];
        #pragma unroll
        for (int j = 0; j < 8; ++j) av[j] = a2[r[j] & 0xFFFFu];
        #pragma unroll
        for (int j = 0; j < 8; ++j) {
            float att = 1.0f / (1.0f + __expf(-(a1s + av[j])));
            float2 xv = bfpair(w[j]);
            if (j & 1) { acc1.x = fmaf(att, xv.x, acc1.x);
                         acc1.y = fmaf(att, xv.y, acc1.y); }
            else       { acc0.x = fmaf(att, xv.x, acc0.x);
                         acc0.y = fmaf(att, xv.y, acc0.y); }
        }
        k += 8;
    }
    if (k + 4 <= end) {
        u32 r[4];
        #pragma unroll
        for (int j = 0; j < 4; ++j) r[j] = skeys[k + j];
        u32 w[4]; float av[4];
        #pragma unroll
        for (int j = 0; j < 4; ++j) w[j] = xjw[(size_t)(r[j] & 0xFFFFu) * 64 + l];
        #pragma unroll
        for (int j = 0; j < 4; ++j) av[j] = a2[r[j] & 0xFFFFu];
        #pragma unroll
        for (int j = 0; j < 4; ++j) {
            float att = 1.0f / (1.0f + __expf(-(a1s + av[j])));
            float2 xv = bfpair(w[j]);
            if (j & 1) { acc1.x = fmaf(att, xv.x, acc1.x);
                         acc1.y = fmaf(att, xv.y, acc1.y); }
            else       { acc0.x = fmaf(att, xv.x, acc0.x);
                         acc0.y = fmaf(att, xv.y, acc0.y); }
        }
        k += 4;
    }
    for (; k < end; ++k) {
        u32 cur = skeys[k];
        float att = 1.0f / (1.0f + __expf(-(a1s + a2[cur & 0xFFFFu])));
        float2 xv = bfpair(xjw[(size_t)(cur & 0xFFFFu) * 64 + l]);
        acc0.x = fmaf(att, xv.x, acc0.x);
        acc0.y = fmaf(att, xv.y, acc0.y);
    }
    acc0.x += acc1.x;
    acc0.y += acc1.y;

    if constexpr (BF16) ((u32*)outv)[(size_t)s * 64 + l] = packbf(acc0.x, acc0.y);
    else                ((float2*)outv)[(size_t)s * 64 + l] = acc0;
}

extern "C" void kernel_launch(void* const* d_in, const int* in_sizes, int n_in,
                              void* d_out, int out_size, void* d_ws, size_t ws_size,
                              hipStream_t stream)
{
    const void* x0  = d_in[0];
    /* d_in[1] = x1: unused by the reference computation */
    const int*  ei  = (const int*)d_in[2];
    const void* W1  = d_in[3];
    const void* b1  = d_in[4];
    const void* W2  = d_in[5];
    const void* b2  = d_in[6];
    const void* a1w = d_in[7];
    const void* a1b = d_in[8];
    const void* a2w = d_in[9];
    const void* a2b = d_in[10];

    const int n = in_sizes[0] / DIM;        // 50000 (< 65536: u16 node ids)
    const int e = in_sizes[2] / 2;          // 800000
    const int nblk = (e + CHUNK - 1) / CHUNK;   // 391 (<= 512 for scan1)

    // ws: flags | xj | a1 | a2 | keys0 | keys1 | keys2 | cntA offA cntB offB
    //     | totA baseA totB baseB | ptr
    char* ws = (char*)d_ws;
    int* flags = (int*)ws;
    size_t off = 1024;
    u16* xj = (u16*)(ws + off);
    off += (size_t)n * DIM * sizeof(u16);   off = (off + 255) & ~(size_t)255;
    float* a1 = (float*)(ws + off);
    off += (size_t)n * sizeof(float);       off = (off + 255) & ~(size_t)255;
    float* a2 = (float*)(ws + off);
    off += (size_t)n * sizeof(float);       off = (off + 255) & ~(size_t)255;
    u32* keys0 = (u32*)(ws + off);
    off += (size_t)e * sizeof(u32);         off = (off + 255) & ~(size_t)255;
    u32* keys1 = (u32*)(ws + off);
    off += (size_t)e * sizeof(u32);         off = (off + 255) & ~(size_t)255;
    u32* keys2 = (u32*)(ws + off);
    off += (size_t)e * sizeof(u32);         off = (off + 255) & ~(size_t)255;
    int* cntA = (int*)(ws + off);
    off += (size_t)256 * nblk * sizeof(int); off = (off + 255) & ~(size_t)255;
    int* offA = (int*)(ws + off);
    off += (size_t)256 * nblk * sizeof(int); off = (off + 255) & ~(size_t)255;
    int* cntB = (int*)(ws + off);
    off += (size_t)256 * nblk * sizeof(int); off = (off + 255) & ~(size_t)255;
    int* offB = (int*)(ws + off);
    off += (size_t)256 * nblk * sizeof(int); off = (off + 255) & ~(size_t)255;
    int* totA = (int*)(ws + off);  off += 1024;
    int* baseA = (int*)(ws + off); off += 1024;
    int* totB = (int*)(ws + off);  off += 1024;
    int* baseB = (int*)(ws + off); off += 1024;
    int* ptr = (int*)(ws + off);
    off += (size_t)(n + 1) * sizeof(int);

    sniff_kernel<<<1, 64, 0, stream>>>((const u32*)x0, ei, flags);

    const int nchunk = (n + 31) / 32;       // 1563
    const int bpg = (nchunk + 3) / 4;       // blocks per matrix
    proj_kernel<true ><<<2 * bpg, 256, 0, stream>>>(x0, W1, b1, W2, b2, a1w, a1b,
                                                    a2w, a2b, xj, a1, a2, flags, n, nchunk, bpg);
    proj_kernel<false><<<2 * bpg, 256, 0, stream>>>(x0, W1, b1, W2, b2, a1w, a1b,
                                                    a2w, a2b, xj, a1, a2, flags, n, nchunk, bpg);

    // radix sort by src (2 x 8-bit LSD), atomic-free CSR build
    countA_kernel<<<nblk, 256, 0, stream>>>(ei, keys0, cntA, flags, e, nblk);
    scan1_kernel<<<256, 256, 0, stream>>>(cntA, offA, totA, nblk);
    scan2_kernel<<<1, 256, 0, stream>>>(totA, baseA);
    reorderA_kernel<<<nblk, 256, 0, stream>>>(keys0, keys1, offA, baseA, e, nblk);
    countB_kernel<<<nblk, 256, 0, stream>>>(keys1, cntB, e, nblk);
    scan1_kernel<<<256, 256, 0, stream>>>(cntB, offB, totB, nblk);
    scan2_kernel<<<1, 256, 0, stream>>>(totB, baseB);
    reorderB_kernel<<<nblk, 64, 0, stream>>>(keys1, keys2, offB, baseB, e, nblk);
    ptr_kernel<<<(e + 255) / 256, 256, 0, stream>>>(keys2, ptr, e, n);

    int gblocks = (n + 3) / 4;
    gather_kernel<true ><<<gblocks, 256, 0, stream>>>(ptr, keys2, a1, a2,
                                                      (const u32*)xj, x0, d_out, flags, n);
    gather_kernel<false><<<gblocks, 256, 0, stream>>>(ptr, keys2, a1, a2,
                                                      (const u32*)xj, x0, d_out, flags, n);
}

// Round 8
// 203.186 us; speedup vs baseline: 1.1343x; 1.1343x over previous
//
#include <hip/hip_runtime.h>
#include <hip/hip_bf16.h>

typedef unsigned int u32;
typedef unsigned short u16;

#define DIM 128
#define LWS 136    // LDS row stride in u16 (128 + 8 pad = 272 B, 16B-aligned)
#define CHUNK 2048 // radix bucket pass: keys per block

typedef __bf16 bfrag __attribute__((ext_vector_type(8)));   // MFMA A/B frag (4 VGPRs)
typedef float  facc  __attribute__((ext_vector_type(4)));   // MFMA C/D frag

__device__ __forceinline__ float2 bfpair(u32 u) {
    union { u32 i; float f; } lo, hi;
    lo.i = (u & 0xFFFFu) << 16;
    hi.i = u & 0xFFFF0000u;
    return make_float2(lo.f, hi.f);
}
__device__ __forceinline__ float bf1(u16 h) {
    union { u32 i; float f; } a; a.i = ((u32)h) << 16; return a.f;
}
__device__ __forceinline__ u16 f2bf(float f) {
    __hip_bfloat16 h = __float2bfloat16(f);   // RNE
    return *reinterpret_cast<u16*>(&h);
}
__device__ __forceinline__ u32 packbf(float x, float y) {
    return (u32)f2bf(x) | ((u32)f2bf(y) << 16);
}

template<bool BF16>
__device__ __forceinline__ float ldf(const void* p, int i) {
    if constexpr (BF16) return bf1(((const u16*)p)[i]);
    else                return ((const float*)p)[i];
}

// load an 8-element bf16 fragment from row-major [*,128] matrix (proven R2-R5)
template<bool BF16>
__device__ __forceinline__ bfrag ldfrag(const void* base, int row, int elt) {
    if constexpr (BF16) {
        const uint4* p = (const uint4*)((const u16*)base + (size_t)row * DIM + elt);
        return __builtin_bit_cast(bfrag, *p);
    } else {
        const float4* p = (const float4*)((const float*)base + (size_t)row * DIM + elt);
        float4 f0 = p[0], f1 = p[1];
        uint4 u = make_uint4(packbf(f0.x, f0.y), packbf(f0.z, f0.w),
                             packbf(f1.x, f1.y), packbf(f1.z, f1.w));
        return __builtin_bit_cast(bfrag, u);
    }
}

// ---------------------------------------------------------------------------
// Sniffer (R2-proven): flags[0]=1 if float tensors are bf16; flags[1]=1 if
// edge_index is int64 layout.
// ---------------------------------------------------------------------------
__global__ __launch_bounds__(64) void sniff_kernel(const u32* __restrict__ x0w,
                                                   const int* __restrict__ eiw,
                                                   int* __restrict__ flags) {
    int l = threadIdx.x;
    u32 w = x0w[l];
    u32 ef = (w >> 7) & 0xFF;                 // exponent of low halfword if bf16
    bool inr = (ef >= 99 && ef <= 141);
    unsigned long long m1 = __ballot(inr);
    bool zodd = (eiw[2 * l + 1] == 0);
    unsigned long long m2 = __ballot(zodd);
    if (l == 0) {
        flags[0] = (__popcll(m1) >= 48) ? 1 : 0;
        flags[1] = (__popcll(m2) >= 32) ? 1 : 0;
    }
}

// ---------------------------------------------------------------------------
// MFMA projection (R4-R8 proven standalone form). One block = 4 chunks of
// one matrix (grp). Produces xj (bf16), a1, a2.
// ---------------------------------------------------------------------------
template<bool BF16>
__global__ __launch_bounds__(256) void proj_kernel(
    const void* __restrict__ x0v,
    const void* __restrict__ W1v, const void* __restrict__ b1v,
    const void* __restrict__ W2v, const void* __restrict__ b2v,
    const void* __restrict__ a1wv, const void* __restrict__ a1bv,
    const void* __restrict__ a2wv, const void* __restrict__ a2bv,
    u16* __restrict__ xj, float* __restrict__ a1, float* __restrict__ a2,
    const int* __restrict__ flags, int n, int nchunk, int bpg)
{
    if ((flags[0] != 0) != BF16) return;      // wrong dtype: ghost launch
    __shared__ u16 lw[128 * LWS];             // ~34 KB

    const int t   = threadIdx.x;
    const int grp = blockIdx.x / bpg;         // 0: W1/a1, 1: W2/a2
    const int cb  = blockIdx.x % bpg;

    const void* Wv  = grp ? W2v  : W1v;
    const void* bv  = grp ? b2v  : b1v;
    const void* awv = grp ? a2wv : a1wv;
    const void* abv = grp ? a2bv : a1bv;
    float* aout     = grp ? a2   : a1;

    // stage W -> LDS as bf16 (16B chunks, padded rows)
    for (int j = t; j < 2048; j += 256) {
        int r = j >> 4, c = j & 15;
        uint4 u;
        if constexpr (BF16) {
            u = *(const uint4*)((const u16*)Wv + (size_t)r * DIM + c * 8);
        } else {
            const float4* p = (const float4*)((const float*)Wv + (size_t)r * DIM + c * 8);
            float4 f0 = p[0], f1 = p[1];
            u = make_uint4(packbf(f0.x, f0.y), packbf(f0.z, f0.w),
                           packbf(f1.x, f1.y), packbf(f1.z, f1.w));
        }
        *(uint4*)(lw + (size_t)r * LWS + c * 8) = u;
    }
    __syncthreads();

    const int wid = t >> 6, l = t & 63;
    const int chunk = cb * 4 + wid;
    if (chunk >= nchunk) return;
    const int r0 = chunk * 32;
    const int lr = l & 15;                    // A row / B col within tile
    const int q  = l >> 4;                    // quad -> k slice, C row group

    bfrag a[2][4];
    #pragma unroll
    for (int rt = 0; rt < 2; ++rt) {
        int row = min(r0 + rt * 16 + lr, n - 1);  // clamp (stores guarded)
        #pragma unroll
        for (int k = 0; k < 4; ++k)
            a[rt][k] = ldfrag<BF16>(x0v, row, k * 32 + q * 8);
    }

    facc acc[2][8];
    #pragma unroll
    for (int rt = 0; rt < 2; ++rt)
        #pragma unroll
        for (int ct = 0; ct < 8; ++ct)
            acc[rt][ct] = (facc){0.f, 0.f, 0.f, 0.f};

    #pragma unroll
    for (int ct = 0; ct < 8; ++ct) {
        bfrag bb[4];
        const u16* lrow = lw + (size_t)(ct * 16 + lr) * LWS;
        #pragma unroll
        for (int k = 0; k < 4; ++k)
            bb[k] = *(const bfrag*)(lrow + k * 32 + q * 8);
        #pragma unroll
        for (int rt = 0; rt < 2; ++rt)
            #pragma unroll
            for (int k = 0; k < 4; ++k)
                acc[rt][ct] = __builtin_amdgcn_mfma_f32_16x16x32_bf16(
                    a[rt][k], bb[k], acc[rt][ct], 0, 0, 0);
    }

    float s[2][4] = {{0.f,0.f,0.f,0.f},{0.f,0.f,0.f,0.f}};
    #pragma unroll
    for (int ct = 0; ct < 8; ++ct) {
        float bc  = ldf<BF16>(bv,  ct * 16 + lr);
        float awc = ldf<BF16>(awv, ct * 16 + lr);
        #pragma unroll
        for (int rt = 0; rt < 2; ++rt)
            #pragma unroll
            for (int reg = 0; reg < 4; ++reg) {
                float v = acc[rt][ct][reg] + bc;
                v = v >= 0.f ? v : 0.2f * v;          // LeakyReLU(0.2)
                int row = r0 + rt * 16 + q * 4 + reg;
                if (grp && row < n)
                    xj[(size_t)row * DIM + ct * 16 + lr] = f2bf(v);
                s[rt][reg] = fmaf(v, awc, s[rt][reg]);
            }
    }
    #pragma unroll
    for (int off = 1; off < 16; off <<= 1)
        #pragma unroll
        for (int rt = 0; rt < 2; ++rt)
            #pragma unroll
            for (int reg = 0; reg < 4; ++reg)
                s[rt][reg] += __shfl_xor(s[rt][reg], off);
    if (lr == 0) {
        float ab = ldf<BF16>(abv, 0);
        #pragma unroll
        for (int rt = 0; rt < 2; ++rt)
            #pragma unroll
            for (int reg = 0; reg < 4; ++reg) {
                int row = r0 + rt * 16 + q * 4 + reg;
                if (row < n) aout[row] = s[rt][reg] + ab;
            }
    }
}

// ---------------------------------------------------------------------------
// R12 MSD bucket CSR build (atomic-free, no stability needed since within-
// segment order is arbitrary). key = (src<<16)|dst; bucket = src>>8 = key>>24.
// Chain: countH -> scan1 -> scan2 -> reorderH (bucket-clustered keys) ->
// bucket_kernel (per-bucket LDS counting sort + ptr + {dst,att} records).
// ---------------------------------------------------------------------------

// countH: emit keys, per-block histogram of key>>24. cnt layout [bin][block].
__global__ __launch_bounds__(256) void countH_kernel(
    const int* __restrict__ ei, u32* __restrict__ keys0,
    int* __restrict__ cnt, const int* __restrict__ flags, int ne, int nblk)
{
    __shared__ int h[256];
    const int b = blockIdx.x, t = threadIdx.x;
    h[t] = 0;
    __syncthreads();
    const bool i64 = flags[1] != 0;
    const int base = b * CHUNK;
    #pragma unroll
    for (int r = 0; r < CHUNK / 256; ++r) {
        int i = base + r * 256 + t;
        if (i < ne) {
            int src = i64 ? ei[2 * i] : ei[i];
            int dst = i64 ? ei[2 * (ne + i)] : ei[ne + i];
            u32 key = ((u32)src << 16) | (u32)dst;
            keys0[i] = key;
            atomicAdd(&h[key >> 24], 1);          // LDS atomic: no fabric
        }
    }
    __syncthreads();
    cnt[t * nblk + b] = h[t];
}

// per-bin exclusive scan over blocks (one block per bin; nblk <= 512). Proven R11.
__global__ __launch_bounds__(256) void scan1_kernel(
    const int* __restrict__ cnt, int* __restrict__ off,
    int* __restrict__ tot, int nblk)
{
    __shared__ int v[512];
    const int d = blockIdx.x, t = threadIdx.x;
    int c0 = (t < nblk) ? cnt[d * nblk + t] : 0;
    int c1 = (t + 256 < nblk) ? cnt[d * nblk + t + 256] : 0;
    v[t] = c0; v[t + 256] = c1;
    __syncthreads();
    for (int s = 1; s < 512; s <<= 1) {
        int a0 = v[t],      b0 = (t >= s) ? v[t - s] : 0;
        int a1 = v[t + 256], b1 = (t + 256 >= s) ? v[t + 256 - s] : 0;
        __syncthreads();
        v[t] = a0 + b0; v[t + 256] = a1 + b1;
        __syncthreads();
    }
    if (t < nblk)       off[d * nblk + t]       = v[t] - c0;        // exclusive
    if (t + 256 < nblk) off[d * nblk + t + 256] = v[t + 256] - c1;
    if (t == 0) tot[d] = v[511];
}

// exclusive scan over 256 bin totals. Proven R11.
__global__ __launch_bounds__(256) void scan2_kernel(
    const int* __restrict__ tot, int* __restrict__ basev)
{
    __shared__ int v[256];
    const int t = threadIdx.x;
    int c = tot[t];
    v[t] = c;
    __syncthreads();
    for (int s = 1; s < 256; s <<= 1) {
        int a = v[t], b = (t >= s) ? v[t - s] : 0;
        __syncthreads();
        v[t] = a + b;
        __syncthreads();
    }
    basev[t] = v[t] - c;
}

// reorderH: scatter keys into bucket-clustered order (unordered within
// bucket — legal). Each (block,bin) owns a contiguous output range.
__global__ __launch_bounds__(256) void reorderH_kernel(
    const u32* __restrict__ kin, u32* __restrict__ kout,
    const int* __restrict__ off, const int* __restrict__ basev,
    int ne, int nblk)
{
    __shared__ int boff[256];
    __shared__ int bcnt[256];
    const int b = blockIdx.x, t = threadIdx.x;
    const int base = b * CHUNK;
    boff[t] = basev[t] + off[t * nblk + b];
    bcnt[t] = 0;
    __syncthreads();
    #pragma unroll
    for (int r = 0; r < CHUNK / 256; ++r) {
        int i = base + r * 256 + t;
        if (i < ne) {
            u32 key = kin[i];
            int d = key >> 24;
            int rk = atomicAdd(&bcnt[d], 1);
            kout[boff[d] + rk] = key;
        }
    }
}

// bucket_kernel: one block per bucket (contiguous src range of 256 nodes).
// LDS counting sort by src&255 -> exact CSR segment: ptr (coalesced) +
// {dst, att} records (bucket-clustered writes). att computed here so gather
// stays lean (R11's in-gather sigmoid pushed VALUBusy to 71%).
__global__ __launch_bounds__(256) void bucket_kernel(
    const u32* __restrict__ keys1, const int* __restrict__ basev,
    const int* __restrict__ tot, const float* __restrict__ a1,
    const float* __restrict__ a2, int* __restrict__ ptr,
    uint2* __restrict__ sorted, int n)
{
    __shared__ int cnt[256];
    __shared__ int sc[256];
    __shared__ int cur[256];
    const int b = blockIdx.x, t = threadIdx.x;
    const int base = basev[b];
    const int size = tot[b];
    cnt[t] = 0;
    __syncthreads();
    for (int i = t; i < size; i += 256)
        atomicAdd(&cnt[(keys1[base + i] >> 16) & 0xFF], 1);
    __syncthreads();
    int c = cnt[t];
    sc[t] = c;
    __syncthreads();
    for (int s = 1; s < 256; s <<= 1) {       // Hillis-Steele inclusive
        int a = sc[t], add = (t >= s) ? sc[t - s] : 0;
        __syncthreads();
        sc[t] = a + add;
        __syncthreads();
    }
    int ex = sc[t] - c;                       // exclusive prefix
    cur[t] = ex;
    int sg = (b << 8) + t;                    // global src id
    if (sg <= n) ptr[sg] = base + ex;         // includes ptr[n] = ne
    __syncthreads();
    for (int i = t; i < size; i += 256) {
        u32 key = keys1[base + i];
        int j   = (key >> 16) & 0xFF;
        int rk  = atomicAdd(&cur[j], 1);
        int src = (int)(key >> 16);
        int dst = (int)(key & 0xFFFFu);
        float av  = a1[src] + a2[dst];
        float att = 1.0f / (1.0f + __expf(-av));
        uint2 rec; rec.x = (u32)dst; rec.y = __float_as_uint(att);
        sorted[base + rk] = rec;
    }
}

// ---------------------------------------------------------------------------
// Gather (R6/R10-proven): one wave per src node, lane l = cols 2l,2l+1.
// Depth-8 software pipeline; dual accumulators; precomputed att records.
// ---------------------------------------------------------------------------
template<bool BF16>
__global__ __launch_bounds__(256) void gather_kernel(
    const int* __restrict__ ptr, const uint2* __restrict__ sorted,
    const u32* __restrict__ xjw, const void* __restrict__ x0v,
    void* __restrict__ outv, const int* __restrict__ flags, int n)
{
    if ((flags[0] != 0) != BF16) return;
    int s = blockIdx.x * 4 + (threadIdx.x >> 6);
    int l = threadIdx.x & 63;
    if (s >= n) return;

    float2 acc0, acc1;
    if constexpr (BF16) acc0 = bfpair(((const u32*)x0v)[(size_t)s * 64 + l]);
    else                acc0 = ((const float2*)x0v)[(size_t)s * 64 + l];
    acc1 = make_float2(0.f, 0.f);

    int k = ptr[s], end = ptr[s + 1];

    while (k + 8 <= end) {
        uint2 r[8];
        #pragma unroll
        for (int j = 0; j < 8; ++j) r[j] = sorted[k + j];
        u32 w[8];
        #pragma unroll
        for (int j = 0; j < 8; ++j) w[j] = xjw[(size_t)r[j].x * 64 + l];
        #pragma unroll
        for (int j = 0; j < 8; ++j) {
            float att = __uint_as_float(r[j].y);
            float2 xv = bfpair(w[j]);
            if (j & 1) { acc1.x = fmaf(att, xv.x, acc1.x);
                         acc1.y = fmaf(att, xv.y, acc1.y); }
            else       { acc0.x = fmaf(att, xv.x, acc0.x);
                         acc0.y = fmaf(att, xv.y, acc0.y); }
        }
        k += 8;
    }
    if (k + 4 <= end) {
        uint2 r[4];
        #pragma unroll
        for (int j = 0; j < 4; ++j) r[j] = sorted[k + j];
        u32 w[4];
        #pragma unroll
        for (int j = 0; j < 4; ++j) w[j] = xjw[(size_t)r[j].x * 64 + l];
        #pragma unroll
        for (int j = 0; j < 4; ++j) {
            float att = __uint_as_float(r[j].y);
            float2 xv = bfpair(w[j]);
            if (j & 1) { acc1.x = fmaf(att, xv.x, acc1.x);
                         acc1.y = fmaf(att, xv.y, acc1.y); }
            else       { acc0.x = fmaf(att, xv.x, acc0.x);
                         acc0.y = fmaf(att, xv.y, acc0.y); }
        }
        k += 4;
    }
    for (; k < end; ++k) {
        uint2 cur = sorted[k];
        float att = __uint_as_float(cur.y);
        float2 xv = bfpair(xjw[(size_t)cur.x * 64 + l]);
        acc0.x = fmaf(att, xv.x, acc0.x);
        acc0.y = fmaf(att, xv.y, acc0.y);
    }
    acc0.x += acc1.x;
    acc0.y += acc1.y;

    if constexpr (BF16) ((u32*)outv)[(size_t)s * 64 + l] = packbf(acc0.x, acc0.y);
    else                ((float2*)outv)[(size_t)s * 64 + l] = acc0;
}

extern "C" void kernel_launch(void* const* d_in, const int* in_sizes, int n_in,
                              void* d_out, int out_size, void* d_ws, size_t ws_size,
                              hipStream_t stream)
{
    const void* x0  = d_in[0];
    /* d_in[1] = x1: unused by the reference computation */
    const int*  ei  = (const int*)d_in[2];
    const void* W1  = d_in[3];
    const void* b1  = d_in[4];
    const void* W2  = d_in[5];
    const void* b2  = d_in[6];
    const void* a1w = d_in[7];
    const void* a1b = d_in[8];
    const void* a2w = d_in[9];
    const void* a2b = d_in[10];

    const int n = in_sizes[0] / DIM;        // 50000 (< 65536: u16 node ids)
    const int e = in_sizes[2] / 2;          // 800000
    const int nblk = (e + CHUNK - 1) / CHUNK;   // 391 (<= 512 for scan1)

    // ws: flags | xj | a1 | a2 | keys0 | keys1 | cnt | off | tot | base |
    //     ptr | sorted(uint2)
    char* ws = (char*)d_ws;
    int* flags = (int*)ws;
    size_t off = 1024;
    u16* xj = (u16*)(ws + off);
    off += (size_t)n * DIM * sizeof(u16);   off = (off + 255) & ~(size_t)255;
    float* a1 = (float*)(ws + off);
    off += (size_t)n * sizeof(float);       off = (off + 255) & ~(size_t)255;
    float* a2 = (float*)(ws + off);
    off += (size_t)n * sizeof(float);       off = (off + 255) & ~(size_t)255;
    u32* keys0 = (u32*)(ws + off);
    off += (size_t)e * sizeof(u32);         off = (off + 255) & ~(size_t)255;
    u32* keys1 = (u32*)(ws + off);
    off += (size_t)e * sizeof(u32);         off = (off + 255) & ~(size_t)255;
    int* cntH = (int*)(ws + off);
    off += (size_t)256 * nblk * sizeof(int); off = (off + 255) & ~(size_t)255;
    int* offH = (int*)(ws + off);
    off += (size_t)256 * nblk * sizeof(int); off = (off + 255) & ~(size_t)255;
    int* totH = (int*)(ws + off);  off += 1024;
    int* baseH = (int*)(ws + off); off += 1024;
    int* ptr = (int*)(ws + off);
    off += (size_t)(n + 1) * sizeof(int);   off = (off + 255) & ~(size_t)255;
    uint2* sorted = (uint2*)(ws + off);

    sniff_kernel<<<1, 64, 0, stream>>>((const u32*)x0, ei, flags);

    const int nchunk = (n + 31) / 32;       // 1563
    const int bpg = (nchunk + 3) / 4;       // blocks per matrix
    proj_kernel<true ><<<2 * bpg, 256, 0, stream>>>(x0, W1, b1, W2, b2, a1w, a1b,
                                                    a2w, a2b, xj, a1, a2, flags, n, nchunk, bpg);
    proj_kernel<false><<<2 * bpg, 256, 0, stream>>>(x0, W1, b1, W2, b2, a1w, a1b,
                                                    a2w, a2b, xj, a1, a2, flags, n, nchunk, bpg);

    // MSD bucket CSR build (atomic-free)
    countH_kernel<<<nblk, 256, 0, stream>>>(ei, keys0, cntH, flags, e, nblk);
    scan1_kernel<<<256, 256, 0, stream>>>(cntH, offH, totH, nblk);
    scan2_kernel<<<1, 256, 0, stream>>>(totH, baseH);
    reorderH_kernel<<<nblk, 256, 0, stream>>>(keys0, keys1, offH, baseH, e, nblk);
    const int nbucket = (n >> 8) + 1;       // 196
    bucket_kernel<<<nbucket, 256, 0, stream>>>(keys1, baseH, totH, a1, a2,
                                               ptr, sorted, n);

    int gblocks = (n + 3) / 4;
    gather_kernel<true ><<<gblocks, 256, 0, stream>>>(ptr, sorted, (const u32*)xj,
                                                      x0, d_out, flags, n);
    gather_kernel<false><<<gblocks, 256, 0, stream>>>(ptr, sorted, (const u32*)xj,
                                                      x0, d_out, flags, n);
}

// Round 9
// 201.519 us; speedup vs baseline: 1.1436x; 1.0083x over previous
//
#include <hip/hip_runtime.h>
#include <hip/hip_bf16.h>

typedef unsigned int u32;
typedef unsigned short u16;

#define DIM 128
#define LWS 136    // LDS row stride in u16 (128 + 8 pad = 272 B, 16B-aligned)
#define CHUNK 2048 // radix bucket pass: keys per block

typedef __bf16 bfrag __attribute__((ext_vector_type(8)));   // MFMA A/B frag (4 VGPRs)
typedef float  facc  __attribute__((ext_vector_type(4)));   // MFMA C/D frag

__device__ __forceinline__ float2 bfpair(u32 u) {
    union { u32 i; float f; } lo, hi;
    lo.i = (u & 0xFFFFu) << 16;
    hi.i = u & 0xFFFF0000u;
    return make_float2(lo.f, hi.f);
}
__device__ __forceinline__ float bf1(u16 h) {
    union { u32 i; float f; } a; a.i = ((u32)h) << 16; return a.f;
}
__device__ __forceinline__ u16 f2bf(float f) {
    __hip_bfloat16 h = __float2bfloat16(f);   // RNE
    return *reinterpret_cast<u16*>(&h);
}
__device__ __forceinline__ u32 packbf(float x, float y) {
    return (u32)f2bf(x) | ((u32)f2bf(y) << 16);
}

template<bool BF16>
__device__ __forceinline__ float ldf(const void* p, int i) {
    if constexpr (BF16) return bf1(((const u16*)p)[i]);
    else                return ((const float*)p)[i];
}

// load an 8-element bf16 fragment from row-major [*,128] matrix (proven R2-R5)
template<bool BF16>
__device__ __forceinline__ bfrag ldfrag(const void* base, int row, int elt) {
    if constexpr (BF16) {
        const uint4* p = (const uint4*)((const u16*)base + (size_t)row * DIM + elt);
        return __builtin_bit_cast(bfrag, *p);
    } else {
        const float4* p = (const float4*)((const float*)base + (size_t)row * DIM + elt);
        float4 f0 = p[0], f1 = p[1];
        uint4 u = make_uint4(packbf(f0.x, f0.y), packbf(f0.z, f0.w),
                             packbf(f1.x, f1.y), packbf(f1.z, f1.w));
        return __builtin_bit_cast(bfrag, u);
    }
}

// ---------------------------------------------------------------------------
// Sniffer (R2-proven): flags[0]=1 if float tensors are bf16; flags[1]=1 if
// edge_index is int64 layout.
// ---------------------------------------------------------------------------
__global__ __launch_bounds__(64) void sniff_kernel(const u32* __restrict__ x0w,
                                                   const int* __restrict__ eiw,
                                                   int* __restrict__ flags) {
    int l = threadIdx.x;
    u32 w = x0w[l];
    u32 ef = (w >> 7) & 0xFF;                 // exponent of low halfword if bf16
    bool inr = (ef >= 99 && ef <= 141);
    unsigned long long m1 = __ballot(inr);
    bool zodd = (eiw[2 * l + 1] == 0);
    unsigned long long m2 = __ballot(zodd);
    if (l == 0) {
        flags[0] = (__popcll(m1) >= 48) ? 1 : 0;
        flags[1] = (__popcll(m2) >= 32) ? 1 : 0;
    }
}

// ---------------------------------------------------------------------------
// Proj body (R4-R8 proven math), templated on dtype, called under a runtime-
// uniform branch (R13: no more ghost launches). lw is kernel-scope LDS.
// ---------------------------------------------------------------------------
template<bool BF16>
__device__ __forceinline__ void proj_body(
    u16* lw, int pid, int t,
    const void* __restrict__ x0v,
    const void* __restrict__ W1v, const void* __restrict__ b1v,
    const void* __restrict__ W2v, const void* __restrict__ b2v,
    const void* __restrict__ a1wv, const void* __restrict__ a1bv,
    const void* __restrict__ a2wv, const void* __restrict__ a2bv,
    u16* __restrict__ xj, float* __restrict__ a1, float* __restrict__ a2,
    int n, int nchunk, int bpg)
{
    const int grp = pid / bpg;                // 0: W1/a1, 1: W2/a2
    const int cb  = pid % bpg;

    const void* Wv  = grp ? W2v  : W1v;
    const void* bv  = grp ? b2v  : b1v;
    const void* awv = grp ? a2wv : a1wv;
    const void* abv = grp ? a2bv : a1bv;
    float* aout     = grp ? a2   : a1;

    // stage W -> LDS as bf16 (16B chunks, padded rows)
    for (int j = t; j < 2048; j += 256) {
        int r = j >> 4, c = j & 15;
        uint4 u;
        if constexpr (BF16) {
            u = *(const uint4*)((const u16*)Wv + (size_t)r * DIM + c * 8);
        } else {
            const float4* p = (const float4*)((const float*)Wv + (size_t)r * DIM + c * 8);
            float4 f0 = p[0], f1 = p[1];
            u = make_uint4(packbf(f0.x, f0.y), packbf(f0.z, f0.w),
                           packbf(f1.x, f1.y), packbf(f1.z, f1.w));
        }
        *(uint4*)(lw + (size_t)r * LWS + c * 8) = u;
    }
    __syncthreads();

    const int wid = t >> 6, l = t & 63;
    const int chunk = cb * 4 + wid;
    if (chunk >= nchunk) return;
    const int r0 = chunk * 32;
    const int lr = l & 15;                    // A row / B col within tile
    const int q  = l >> 4;                    // quad -> k slice, C row group

    bfrag a[2][4];
    #pragma unroll
    for (int rt = 0; rt < 2; ++rt) {
        int row = min(r0 + rt * 16 + lr, n - 1);  // clamp (stores guarded)
        #pragma unroll
        for (int k = 0; k < 4; ++k)
            a[rt][k] = ldfrag<BF16>(x0v, row, k * 32 + q * 8);
    }

    facc acc[2][8];
    #pragma unroll
    for (int rt = 0; rt < 2; ++rt)
        #pragma unroll
        for (int ct = 0; ct < 8; ++ct)
            acc[rt][ct] = (facc){0.f, 0.f, 0.f, 0.f};

    #pragma unroll
    for (int ct = 0; ct < 8; ++ct) {
        bfrag bb[4];
        const u16* lrow = lw + (size_t)(ct * 16 + lr) * LWS;
        #pragma unroll
        for (int k = 0; k < 4; ++k)
            bb[k] = *(const bfrag*)(lrow + k * 32 + q * 8);
        #pragma unroll
        for (int rt = 0; rt < 2; ++rt)
            #pragma unroll
            for (int k = 0; k < 4; ++k)
                acc[rt][ct] = __builtin_amdgcn_mfma_f32_16x16x32_bf16(
                    a[rt][k], bb[k], acc[rt][ct], 0, 0, 0);
    }

    float s[2][4] = {{0.f,0.f,0.f,0.f},{0.f,0.f,0.f,0.f}};
    #pragma unroll
    for (int ct = 0; ct < 8; ++ct) {
        float bc  = ldf<BF16>(bv,  ct * 16 + lr);
        float awc = ldf<BF16>(awv, ct * 16 + lr);
        #pragma unroll
        for (int rt = 0; rt < 2; ++rt)
            #pragma unroll
            for (int reg = 0; reg < 4; ++reg) {
                float v = acc[rt][ct][reg] + bc;
                v = v >= 0.f ? v : 0.2f * v;          // LeakyReLU(0.2)
                int row = r0 + rt * 16 + q * 4 + reg;
                if (grp && row < n)
                    xj[(size_t)row * DIM + ct * 16 + lr] = f2bf(v);
                s[rt][reg] = fmaf(v, awc, s[rt][reg]);
            }
    }
    #pragma unroll
    for (int off = 1; off < 16; off <<= 1)
        #pragma unroll
        for (int rt = 0; rt < 2; ++rt)
            #pragma unroll
            for (int reg = 0; reg < 4; ++reg)
                s[rt][reg] += __shfl_xor(s[rt][reg], off);
    if (lr == 0) {
        float ab = ldf<BF16>(abv, 0);
        #pragma unroll
        for (int rt = 0; rt < 2; ++rt)
            #pragma unroll
            for (int reg = 0; reg < 4; ++reg) {
                int row = r0 + rt * 16 + q * 4 + reg;
                if (row < n) aout[row] = s[rt][reg] + ab;
            }
    }
}

// ---------------------------------------------------------------------------
// R13 fused proj + countH (R9-proven 1 : S-1 interleave; countH is proj-
// independent and hides under MFMA). Runtime dtype branch (uniform).
// countH: emit keys (src<<16|dst), per-block histogram of key>>24.
// ---------------------------------------------------------------------------
__global__ __launch_bounds__(256) void proj_count_kernel(
    const void* __restrict__ x0v,
    const void* __restrict__ W1v, const void* __restrict__ b1v,
    const void* __restrict__ W2v, const void* __restrict__ b2v,
    const void* __restrict__ a1wv, const void* __restrict__ a1bv,
    const void* __restrict__ a2wv, const void* __restrict__ a2bv,
    u16* __restrict__ xj, float* __restrict__ a1, float* __restrict__ a2,
    const int* __restrict__ ei, u32* __restrict__ keys0, int* __restrict__ cnt,
    const int* __restrict__ flags, int n, int ne, int nchunk, int bpg,
    int nblk, int S)
{
    __shared__ u16 lw[128 * LWS];             // ~34 KB (count blocks carry it)
    __shared__ int h[256];
    const int b = blockIdx.x, t = threadIdx.x;
    const int nbp = 2 * bpg;

    if (b % S != 0) {
        // ---- countH part ----
        int hb = (b / S) * (S - 1) + (b % S) - 1;
        if (hb >= nblk) return;               // spare blocks: no OOB cnt write
        h[t] = 0;
        __syncthreads();
        const bool i64 = flags[1] != 0;
        const int base = hb * CHUNK;
        #pragma unroll
        for (int r = 0; r < CHUNK / 256; ++r) {
            int i = base + r * 256 + t;
            if (i < ne) {
                int src = i64 ? ei[2 * i] : ei[i];
                int dst = i64 ? ei[2 * (ne + i)] : ei[ne + i];
                u32 key = ((u32)src << 16) | (u32)dst;
                keys0[i] = key;
                atomicAdd(&h[key >> 24], 1);  // LDS atomic: no fabric
            }
        }
        __syncthreads();
        cnt[t * nblk + hb] = h[t];
        return;
    }

    const int pid = b / S;
    if (pid >= nbp) return;
    if (flags[0] != 0)
        proj_body<true >(lw, pid, t, x0v, W1v, b1v, W2v, b2v, a1wv, a1bv,
                         a2wv, a2bv, xj, a1, a2, n, nchunk, bpg);
    else
        proj_body<false>(lw, pid, t, x0v, W1v, b1v, W2v, b2v, a1wv, a1bv,
                         a2wv, a2bv, xj, a1, a2, n, nchunk, bpg);
}

// per-bin exclusive scan over blocks (one block per bin; nblk <= 512). Proven R11.
__global__ __launch_bounds__(256) void scan1_kernel(
    const int* __restrict__ cnt, int* __restrict__ off,
    int* __restrict__ tot, int nblk)
{
    __shared__ int v[512];
    const int d = blockIdx.x, t = threadIdx.x;
    int c0 = (t < nblk) ? cnt[d * nblk + t] : 0;
    int c1 = (t + 256 < nblk) ? cnt[d * nblk + t + 256] : 0;
    v[t] = c0; v[t + 256] = c1;
    __syncthreads();
    for (int s = 1; s < 512; s <<= 1) {
        int a0 = v[t],      b0 = (t >= s) ? v[t - s] : 0;
        int a1 = v[t + 256], b1 = (t + 256 >= s) ? v[t + 256 - s] : 0;
        __syncthreads();
        v[t] = a0 + b0; v[t + 256] = a1 + b1;
        __syncthreads();
    }
    if (t < nblk)       off[d * nblk + t]       = v[t] - c0;        // exclusive
    if (t + 256 < nblk) off[d * nblk + t + 256] = v[t + 256] - c1;
    if (t == 0) tot[d] = v[511];
}

// exclusive scan over 256 bin totals. Proven R11.
__global__ __launch_bounds__(256) void scan2_kernel(
    const int* __restrict__ tot, int* __restrict__ basev)
{
    __shared__ int v[256];
    const int t = threadIdx.x;
    int c = tot[t];
    v[t] = c;
    __syncthreads();
    for (int s = 1; s < 256; s <<= 1) {
        int a = v[t], b = (t >= s) ? v[t - s] : 0;
        __syncthreads();
        v[t] = a + b;
        __syncthreads();
    }
    basev[t] = v[t] - c;
}

// reorderH (R12-proven): scatter keys into bucket-clustered order.
__global__ __launch_bounds__(256) void reorderH_kernel(
    const u32* __restrict__ kin, u32* __restrict__ kout,
    const int* __restrict__ off, const int* __restrict__ basev,
    int ne, int nblk)
{
    __shared__ int boff[256];
    __shared__ int bcnt[256];
    const int b = blockIdx.x, t = threadIdx.x;
    const int base = b * CHUNK;
    boff[t] = basev[t] + off[t * nblk + b];
    bcnt[t] = 0;
    __syncthreads();
    #pragma unroll
    for (int r = 0; r < CHUNK / 256; ++r) {
        int i = base + r * 256 + t;
        if (i < ne) {
            u32 key = kin[i];
            int d = key >> 24;
            int rk = atomicAdd(&bcnt[d], 1);
            kout[boff[d] + rk] = key;
        }
    }
}

// bucket_kernel (R12-proven structure): one block per bucket (256 src ids).
// LDS counting sort by src&255 -> ptr + records. R13: record compressed to
// u32 = (att_u16_fixedpoint << 16) | dst. att error 7.6e-6 — ~4000x below
// the bf16 output quantum (0.03125) that dominates absmax.
__global__ __launch_bounds__(256) void bucket_kernel(
    const u32* __restrict__ keys1, const int* __restrict__ basev,
    const int* __restrict__ tot, const float* __restrict__ a1,
    const float* __restrict__ a2, int* __restrict__ ptr,
    u32* __restrict__ sorted, int n)
{
    __shared__ int cnt[256];
    __shared__ int sc[256];
    __shared__ int cur[256];
    const int b = blockIdx.x, t = threadIdx.x;
    const int base = basev[b];
    const int size = tot[b];
    cnt[t] = 0;
    __syncthreads();
    for (int i = t; i < size; i += 256)
        atomicAdd(&cnt[(keys1[base + i] >> 16) & 0xFF], 1);
    __syncthreads();
    int c = cnt[t];
    sc[t] = c;
    __syncthreads();
    for (int s = 1; s < 256; s <<= 1) {       // Hillis-Steele inclusive
        int a = sc[t], add = (t >= s) ? sc[t - s] : 0;
        __syncthreads();
        sc[t] = a + add;
        __syncthreads();
    }
    int ex = sc[t] - c;                       // exclusive prefix
    cur[t] = ex;
    int sg = (b << 8) + t;                    // global src id
    if (sg <= n) ptr[sg] = base + ex;         // includes ptr[n] = ne
    __syncthreads();
    for (int i = t; i < size; i += 256) {
        u32 key = keys1[base + i];
        int j   = (key >> 16) & 0xFF;
        int rk  = atomicAdd(&cur[j], 1);
        int src = (int)(key >> 16);
        int dst = (int)(key & 0xFFFFu);
        float av  = a1[src] + a2[dst];
        float att = 1.0f / (1.0f + __expf(-av));
        u32 a16 = (u32)lrintf(att * 65535.0f);        // in [0, 65535]
        sorted[base + rk] = (a16 << 16) | (u32)dst;
    }
}

// ---------------------------------------------------------------------------
// Gather (R6-proven MLP structure, R13: depth-16 main chunk over compressed
// u32 records; runtime dtype branch). One wave per src node, lane l = cols
// 2l,2l+1. att decode: uniform (r>>16)*(1/65535).
// ---------------------------------------------------------------------------
#define ATTDEC(r) ((float)((r) >> 16) * (1.0f / 65535.0f))

__global__ __launch_bounds__(256) void gather_kernel(
    const int* __restrict__ ptr, const u32* __restrict__ sorted,
    const u32* __restrict__ xjw, const void* __restrict__ x0v,
    void* __restrict__ outv, const int* __restrict__ flags, int n)
{
    const bool bf16 = flags[0] != 0;
    int s = blockIdx.x * 4 + (threadIdx.x >> 6);
    int l = threadIdx.x & 63;
    if (s >= n) return;

    float2 acc0, acc1;
    if (bf16) acc0 = bfpair(((const u32*)x0v)[(size_t)s * 64 + l]);
    else      acc0 = ((const float2*)x0v)[(size_t)s * 64 + l];
    acc1 = make_float2(0.f, 0.f);

    int k = ptr[s], end = ptr[s + 1];

    // main chunks: 16 edges in flight
    while (k + 16 <= end) {
        u32 r[16];
        #pragma unroll
        for (int j = 0; j < 16; ++j) r[j] = sorted[k + j];
        u32 w[16];
        #pragma unroll
        for (int j = 0; j < 16; ++j) w[j] = xjw[(size_t)(r[j] & 0xFFFFu) * 64 + l];
        #pragma unroll
        for (int j = 0; j < 16; ++j) {
            float att = ATTDEC(r[j]);
            float2 xv = bfpair(w[j]);
            if (j & 1) { acc1.x = fmaf(att, xv.x, acc1.x);
                         acc1.y = fmaf(att, xv.y, acc1.y); }
            else       { acc0.x = fmaf(att, xv.x, acc0.x);
                         acc0.y = fmaf(att, xv.y, acc0.y); }
        }
        k += 16;
    }
    if (k + 8 <= end) {
        u32 r[8];
        #pragma unroll
        for (int j = 0; j < 8; ++j) r[j] = sorted[k + j];
        u32 w[8];
        #pragma unroll
        for (int j = 0; j < 8; ++j) w[j] = xjw[(size_t)(r[j] & 0xFFFFu) * 64 + l];
        #pragma unroll
        for (int j = 0; j < 8; ++j) {
            float att = ATTDEC(r[j]);
            float2 xv = bfpair(w[j]);
            if (j & 1) { acc1.x = fmaf(att, xv.x, acc1.x);
                         acc1.y = fmaf(att, xv.y, acc1.y); }
            else       { acc0.x = fmaf(att, xv.x, acc0.x);
                         acc0.y = fmaf(att, xv.y, acc0.y); }
        }
        k += 8;
    }
    if (k + 4 <= end) {
        u32 r[4];
        #pragma unroll
        for (int j = 0; j < 4; ++j) r[j] = sorted[k + j];
        u32 w[4];
        #pragma unroll
        for (int j = 0; j < 4; ++j) w[j] = xjw[(size_t)(r[j] & 0xFFFFu) * 64 + l];
        #pragma unroll
        for (int j = 0; j < 4; ++j) {
            float att = ATTDEC(r[j]);
            float2 xv = bfpair(w[j]);
            if (j & 1) { acc1.x = fmaf(att, xv.x, acc1.x);
                         acc1.y = fmaf(att, xv.y, acc1.y); }
            else       { acc0.x = fmaf(att, xv.x, acc0.x);
                         acc0.y = fmaf(att, xv.y, acc0.y); }
        }
        k += 4;
    }
    for (; k < end; ++k) {
        u32 cur = sorted[k];
        float att = ATTDEC(cur);
        float2 xv = bfpair(xjw[(size_t)(cur & 0xFFFFu) * 64 + l]);
        acc0.x = fmaf(att, xv.x, acc0.x);
        acc0.y = fmaf(att, xv.y, acc0.y);
    }
    acc0.x += acc1.x;
    acc0.y += acc1.y;

    if (bf16) ((u32*)outv)[(size_t)s * 64 + l] = packbf(acc0.x, acc0.y);
    else      ((float2*)outv)[(size_t)s * 64 + l] = acc0;
}

extern "C" void kernel_launch(void* const* d_in, const int* in_sizes, int n_in,
                              void* d_out, int out_size, void* d_ws, size_t ws_size,
                              hipStream_t stream)
{
    const void* x0  = d_in[0];
    /* d_in[1] = x1: unused by the reference computation */
    const int*  ei  = (const int*)d_in[2];
    const void* W1  = d_in[3];
    const void* b1  = d_in[4];
    const void* W2  = d_in[5];
    const void* b2  = d_in[6];
    const void* a1w = d_in[7];
    const void* a1b = d_in[8];
    const void* a2w = d_in[9];
    const void* a2b = d_in[10];

    const int n = in_sizes[0] / DIM;        // 50000 (< 65536: u16 node ids)
    const int e = in_sizes[2] / 2;          // 800000
    const int nblk = (e + CHUNK - 1) / CHUNK;   // 391 (<= 512 for scan1)

    // ws: flags | xj | a1 | a2 | keys0 | keys1 | cnt | off | tot | base |
    //     ptr | sorted(u32)
    char* ws = (char*)d_ws;
    int* flags = (int*)ws;
    size_t off = 1024;
    u16* xj = (u16*)(ws + off);
    off += (size_t)n * DIM * sizeof(u16);   off = (off + 255) & ~(size_t)255;
    float* a1 = (float*)(ws + off);
    off += (size_t)n * sizeof(float);       off = (off + 255) & ~(size_t)255;
    float* a2 = (float*)(ws + off);
    off += (size_t)n * sizeof(float);       off = (off + 255) & ~(size_t)255;
    u32* keys0 = (u32*)(ws + off);
    off += (size_t)e * sizeof(u32);         off = (off + 255) & ~(size_t)255;
    u32* keys1 = (u32*)(ws + off);
    off += (size_t)e * sizeof(u32);         off = (off + 255) & ~(size_t)255;
    int* cntH = (int*)(ws + off);
    off += (size_t)256 * nblk * sizeof(int); off = (off + 255) & ~(size_t)255;
    int* offH = (int*)(ws + off);
    off += (size_t)256 * nblk * sizeof(int); off = (off + 255) & ~(size_t)255;
    int* totH = (int*)(ws + off);  off += 1024;
    int* baseH = (int*)(ws + off); off += 1024;
    int* ptr = (int*)(ws + off);
    off += (size_t)(n + 1) * sizeof(int);   off = (off + 255) & ~(size_t)255;
    u32* sorted = (u32*)(ws + off);

    sniff_kernel<<<1, 64, 0, stream>>>((const u32*)x0, ei, flags);

    const int nchunk = (n + 31) / 32;       // 1563
    const int bpg = (nchunk + 3) / 4;       // blocks per matrix (391)
    const int nbp = 2 * bpg;                // proj blocks (782)
    // interleave 1 proj : (S-1) countH so every CU hosts a mix
    const int S = 1 + (nblk + nbp - 1) / nbp;   // 2
    const int fgrid = nbp * S;                  // 1564

    proj_count_kernel<<<fgrid, 256, 0, stream>>>(x0, W1, b1, W2, b2, a1w, a1b,
        a2w, a2b, xj, a1, a2, ei, keys0, cntH, flags, n, e, nchunk, bpg, nblk, S);

    // MSD bucket CSR build (atomic-free), R12-proven
    scan1_kernel<<<256, 256, 0, stream>>>(cntH, offH, totH, nblk);
    scan2_kernel<<<1, 256, 0, stream>>>(totH, baseH);
    reorderH_kernel<<<nblk, 256, 0, stream>>>(keys0, keys1, offH, baseH, e, nblk);
    const int nbucket = (n >> 8) + 1;       // 196
    bucket_kernel<<<nbucket, 256, 0, stream>>>(keys1, baseH, totH, a1, a2,
                                               ptr, sorted, n);

    int gblocks = (n + 3) / 4;
    gather_kernel<<<gblocks, 256, 0, stream>>>(ptr, sorted, (const u32*)xj,
                                               x0, d_out, flags, n);
}

// Round 10
// 201.139 us; speedup vs baseline: 1.1458x; 1.0019x over previous
//
#include <hip/hip_runtime.h>
#include <hip/hip_bf16.h>

typedef unsigned int u32;
typedef unsigned short u16;

#define DIM 128
#define LWS 136    // LDS row stride in u16 (128 + 8 pad = 272 B, 16B-aligned)
#define CHUNK 2048 // radix bucket pass: keys per block

typedef __bf16 bfrag __attribute__((ext_vector_type(8)));   // MFMA A/B frag (4 VGPRs)
typedef float  facc  __attribute__((ext_vector_type(4)));   // MFMA C/D frag

__device__ __forceinline__ float2 bfpair(u32 u) {
    union { u32 i; float f; } lo, hi;
    lo.i = (u & 0xFFFFu) << 16;
    hi.i = u & 0xFFFF0000u;
    return make_float2(lo.f, hi.f);
}
__device__ __forceinline__ float bf1(u16 h) {
    union { u32 i; float f; } a; a.i = ((u32)h) << 16; return a.f;
}
__device__ __forceinline__ u16 f2bf(float f) {
    __hip_bfloat16 h = __float2bfloat16(f);   // RNE
    return *reinterpret_cast<u16*>(&h);
}
__device__ __forceinline__ u32 packbf(float x, float y) {
    return (u32)f2bf(x) | ((u32)f2bf(y) << 16);
}

template<bool BF16>
__device__ __forceinline__ float ldf(const void* p, int i) {
    if constexpr (BF16) return bf1(((const u16*)p)[i]);
    else                return ((const float*)p)[i];
}

// load an 8-element bf16 fragment from row-major [*,128] matrix (proven R2-R5)
template<bool BF16>
__device__ __forceinline__ bfrag ldfrag(const void* base, int row, int elt) {
    if constexpr (BF16) {
        const uint4* p = (const uint4*)((const u16*)base + (size_t)row * DIM + elt);
        return __builtin_bit_cast(bfrag, *p);
    } else {
        const float4* p = (const float4*)((const float*)base + (size_t)row * DIM + elt);
        float4 f0 = p[0], f1 = p[1];
        uint4 u = make_uint4(packbf(f0.x, f0.y), packbf(f0.z, f0.w),
                             packbf(f1.x, f1.y), packbf(f1.z, f1.w));
        return __builtin_bit_cast(bfrag, u);
    }
}

// ---------------------------------------------------------------------------
// Sniffer (R2-proven): flags[0]=1 if float tensors are bf16; flags[1]=1 if
// edge_index is int64 layout.
// ---------------------------------------------------------------------------
__global__ __launch_bounds__(64) void sniff_kernel(const u32* __restrict__ x0w,
                                                   const int* __restrict__ eiw,
                                                   int* __restrict__ flags) {
    int l = threadIdx.x;
    u32 w = x0w[l];
    u32 ef = (w >> 7) & 0xFF;                 // exponent of low halfword if bf16
    bool inr = (ef >= 99 && ef <= 141);
    unsigned long long m1 = __ballot(inr);
    bool zodd = (eiw[2 * l + 1] == 0);
    unsigned long long m2 = __ballot(zodd);
    if (l == 0) {
        flags[0] = (__popcll(m1) >= 48) ? 1 : 0;
        flags[1] = (__popcll(m2) >= 32) ? 1 : 0;
    }
}

// ---------------------------------------------------------------------------
// Proj body (R4-R8 proven math). R14: A-fragment loads issued BEFORE the
// W->LDS staging (they are independent; previously they sat after the
// barrier, so each block paid W-stage latency + A-load latency SERIALLY —
// the T14 issue-early pattern hides the A-loads under staging+barrier).
// ---------------------------------------------------------------------------
template<bool BF16>
__device__ __forceinline__ void proj_body(
    u16* lw, int pid, int t,
    const void* __restrict__ x0v,
    const void* __restrict__ W1v, const void* __restrict__ b1v,
    const void* __restrict__ W2v, const void* __restrict__ b2v,
    const void* __restrict__ a1wv, const void* __restrict__ a1bv,
    const void* __restrict__ a2wv, const void* __restrict__ a2bv,
    u16* __restrict__ xj, float* __restrict__ a1, float* __restrict__ a2,
    int n, int nchunk, int bpg)
{
    const int grp = pid / bpg;                // 0: W1/a1, 1: W2/a2
    const int cb  = pid % bpg;

    const void* Wv  = grp ? W2v  : W1v;
    const void* bv  = grp ? b2v  : b1v;
    const void* awv = grp ? a2wv : a1wv;
    const void* abv = grp ? a2bv : a1bv;
    float* aout     = grp ? a2   : a1;

    const int wid = t >> 6, l = t & 63;
    const int chunk = cb * 4 + wid;
    const bool active = chunk < nchunk;
    const int r0 = chunk * 32;
    const int lr = l & 15;                    // A row / B col within tile
    const int q  = l >> 4;                    // quad -> k slice, C row group

    // A fragments FIRST (independent of W staging; hides under it)
    bfrag a[2][4];
    if (active) {
        #pragma unroll
        for (int rt = 0; rt < 2; ++rt) {
            int row = min(r0 + rt * 16 + lr, n - 1);  // clamp (stores guarded)
            #pragma unroll
            for (int k = 0; k < 4; ++k)
                a[rt][k] = ldfrag<BF16>(x0v, row, k * 32 + q * 8);
        }
    }

    // stage W -> LDS as bf16 (16B chunks, padded rows)
    for (int j = t; j < 2048; j += 256) {
        int r = j >> 4, c = j & 15;
        uint4 u;
        if constexpr (BF16) {
            u = *(const uint4*)((const u16*)Wv + (size_t)r * DIM + c * 8);
        } else {
            const float4* p = (const float4*)((const float*)Wv + (size_t)r * DIM + c * 8);
            float4 f0 = p[0], f1 = p[1];
            u = make_uint4(packbf(f0.x, f0.y), packbf(f0.z, f0.w),
                           packbf(f1.x, f1.y), packbf(f1.z, f1.w));
        }
        *(uint4*)(lw + (size_t)r * LWS + c * 8) = u;
    }
    __syncthreads();

    if (!active) return;

    facc acc[2][8];
    #pragma unroll
    for (int rt = 0; rt < 2; ++rt)
        #pragma unroll
        for (int ct = 0; ct < 8; ++ct)
            acc[rt][ct] = (facc){0.f, 0.f, 0.f, 0.f};

    #pragma unroll
    for (int ct = 0; ct < 8; ++ct) {
        bfrag bb[4];
        const u16* lrow = lw + (size_t)(ct * 16 + lr) * LWS;
        #pragma unroll
        for (int k = 0; k < 4; ++k)
            bb[k] = *(const bfrag*)(lrow + k * 32 + q * 8);
        #pragma unroll
        for (int rt = 0; rt < 2; ++rt)
            #pragma unroll
            for (int k = 0; k < 4; ++k)
                acc[rt][ct] = __builtin_amdgcn_mfma_f32_16x16x32_bf16(
                    a[rt][k], bb[k], acc[rt][ct], 0, 0, 0);
    }

    float s[2][4] = {{0.f,0.f,0.f,0.f},{0.f,0.f,0.f,0.f}};
    #pragma unroll
    for (int ct = 0; ct < 8; ++ct) {
        float bc  = ldf<BF16>(bv,  ct * 16 + lr);
        float awc = ldf<BF16>(awv, ct * 16 + lr);
        #pragma unroll
        for (int rt = 0; rt < 2; ++rt)
            #pragma unroll
            for (int reg = 0; reg < 4; ++reg) {
                float v = acc[rt][ct][reg] + bc;
                v = v >= 0.f ? v : 0.2f * v;          // LeakyReLU(0.2)
                int row = r0 + rt * 16 + q * 4 + reg;
                if (grp && row < n)
                    xj[(size_t)row * DIM + ct * 16 + lr] = f2bf(v);
                s[rt][reg] = fmaf(v, awc, s[rt][reg]);
            }
    }
    #pragma unroll
    for (int off = 1; off < 16; off <<= 1)
        #pragma unroll
        for (int rt = 0; rt < 2; ++rt)
            #pragma unroll
            for (int reg = 0; reg < 4; ++reg)
                s[rt][reg] += __shfl_xor(s[rt][reg], off);
    if (lr == 0) {
        float ab = ldf<BF16>(abv, 0);
        #pragma unroll
        for (int rt = 0; rt < 2; ++rt)
            #pragma unroll
            for (int reg = 0; reg < 4; ++reg) {
                int row = r0 + rt * 16 + q * 4 + reg;
                if (row < n) aout[row] = s[rt][reg] + ab;
            }
    }
}

// ---------------------------------------------------------------------------
// R13 fused proj + countH (R9-proven 1 : S-1 interleave). Runtime dtype
// branch (uniform). countH: emit keys (src<<16|dst), histogram key>>24.
// ---------------------------------------------------------------------------
__global__ __launch_bounds__(256) void proj_count_kernel(
    const void* __restrict__ x0v,
    const void* __restrict__ W1v, const void* __restrict__ b1v,
    const void* __restrict__ W2v, const void* __restrict__ b2v,
    const void* __restrict__ a1wv, const void* __restrict__ a1bv,
    const void* __restrict__ a2wv, const void* __restrict__ a2bv,
    u16* __restrict__ xj, float* __restrict__ a1, float* __restrict__ a2,
    const int* __restrict__ ei, u32* __restrict__ keys0, int* __restrict__ cnt,
    const int* __restrict__ flags, int n, int ne, int nchunk, int bpg,
    int nblk, int S)
{
    __shared__ u16 lw[128 * LWS];             // ~34 KB (count blocks carry it)
    __shared__ int h[256];
    const int b = blockIdx.x, t = threadIdx.x;
    const int nbp = 2 * bpg;

    if (b % S != 0) {
        // ---- countH part ----
        int hb = (b / S) * (S - 1) + (b % S) - 1;
        if (hb >= nblk) return;               // spare blocks: no OOB cnt write
        h[t] = 0;
        __syncthreads();
        const bool i64 = flags[1] != 0;
        const int base = hb * CHUNK;
        #pragma unroll
        for (int r = 0; r < CHUNK / 256; ++r) {
            int i = base + r * 256 + t;
            if (i < ne) {
                int src = i64 ? ei[2 * i] : ei[i];
                int dst = i64 ? ei[2 * (ne + i)] : ei[ne + i];
                u32 key = ((u32)src << 16) | (u32)dst;
                keys0[i] = key;
                atomicAdd(&h[key >> 24], 1);  // LDS atomic: no fabric
            }
        }
        __syncthreads();
        cnt[t * nblk + hb] = h[t];
        return;
    }

    const int pid = b / S;
    if (pid >= nbp) return;
    if (flags[0] != 0)
        proj_body<true >(lw, pid, t, x0v, W1v, b1v, W2v, b2v, a1wv, a1bv,
                         a2wv, a2bv, xj, a1, a2, n, nchunk, bpg);
    else
        proj_body<false>(lw, pid, t, x0v, W1v, b1v, W2v, b2v, a1wv, a1bv,
                         a2wv, a2bv, xj, a1, a2, n, nchunk, bpg);
}

// per-bin exclusive scan over blocks (one block per bin; nblk <= 512). Proven R11.
__global__ __launch_bounds__(256) void scan1_kernel(
    const int* __restrict__ cnt, int* __restrict__ off,
    int* __restrict__ tot, int nblk)
{
    __shared__ int v[512];
    const int d = blockIdx.x, t = threadIdx.x;
    int c0 = (t < nblk) ? cnt[d * nblk + t] : 0;
    int c1 = (t + 256 < nblk) ? cnt[d * nblk + t + 256] : 0;
    v[t] = c0; v[t + 256] = c1;
    __syncthreads();
    for (int s = 1; s < 512; s <<= 1) {
        int a0 = v[t],      b0 = (t >= s) ? v[t - s] : 0;
        int a1 = v[t + 256], b1 = (t + 256 >= s) ? v[t + 256 - s] : 0;
        __syncthreads();
        v[t] = a0 + b0; v[t + 256] = a1 + b1;
        __syncthreads();
    }
    if (t < nblk)       off[d * nblk + t]       = v[t] - c0;        // exclusive
    if (t + 256 < nblk) off[d * nblk + t + 256] = v[t + 256] - c1;
    if (t == 0) tot[d] = v[511];
}

// exclusive scan over 256 bin totals. Proven R11.
__global__ __launch_bounds__(256) void scan2_kernel(
    const int* __restrict__ tot, int* __restrict__ basev)
{
    __shared__ int v[256];
    const int t = threadIdx.x;
    int c = tot[t];
    v[t] = c;
    __syncthreads();
    for (int s = 1; s < 256; s <<= 1) {
        int a = v[t], b = (t >= s) ? v[t - s] : 0;
        __syncthreads();
        v[t] = a + b;
        __syncthreads();
    }
    basev[t] = v[t] - c;
}

// reorderH (R12-proven): scatter keys into bucket-clustered order.
__global__ __launch_bounds__(256) void reorderH_kernel(
    const u32* __restrict__ kin, u32* __restrict__ kout,
    const int* __restrict__ off, const int* __restrict__ basev,
    int ne, int nblk)
{
    __shared__ int boff[256];
    __shared__ int bcnt[256];
    const int b = blockIdx.x, t = threadIdx.x;
    const int base = b * CHUNK;
    boff[t] = basev[t] + off[t * nblk + b];
    bcnt[t] = 0;
    __syncthreads();
    #pragma unroll
    for (int r = 0; r < CHUNK / 256; ++r) {
        int i = base + r * 256 + t;
        if (i < ne) {
            u32 key = kin[i];
            int d = key >> 24;
            int rk = atomicAdd(&bcnt[d], 1);
            kout[boff[d] + rk] = key;
        }
    }
}

// bucket_kernel (R12-proven structure): one block per bucket (256 src ids).
// LDS counting sort by src&255 -> ptr + records. R13: record compressed to
// u32 = (att_u16_fixedpoint << 16) | dst. att error 7.6e-6 — ~4000x below
// the bf16 output quantum (0.03125) that dominates absmax.
__global__ __launch_bounds__(256) void bucket_kernel(
    const u32* __restrict__ keys1, const int* __restrict__ basev,
    const int* __restrict__ tot, const float* __restrict__ a1,
    const float* __restrict__ a2, int* __restrict__ ptr,
    u32* __restrict__ sorted, int n)
{
    __shared__ int cnt[256];
    __shared__ int sc[256];
    __shared__ int cur[256];
    const int b = blockIdx.x, t = threadIdx.x;
    const int base = basev[b];
    const int size = tot[b];
    cnt[t] = 0;
    __syncthreads();
    for (int i = t; i < size; i += 256)
        atomicAdd(&cnt[(keys1[base + i] >> 16) & 0xFF], 1);
    __syncthreads();
    int c = cnt[t];
    sc[t] = c;
    __syncthreads();
    for (int s = 1; s < 256; s <<= 1) {       // Hillis-Steele inclusive
        int a = sc[t], add = (t >= s) ? sc[t - s] : 0;
        __syncthreads();
        sc[t] = a + add;
        __syncthreads();
    }
    int ex = sc[t] - c;                       // exclusive prefix
    cur[t] = ex;
    int sg = (b << 8) + t;                    // global src id
    if (sg <= n) ptr[sg] = base + ex;         // includes ptr[n] = ne
    __syncthreads();
    for (int i = t; i < size; i += 256) {
        u32 key = keys1[base + i];
        int j   = (key >> 16) & 0xFF;
        int rk  = atomicAdd(&cur[j], 1);
        int src = (int)(key >> 16);
        int dst = (int)(key & 0xFFFFu);
        float av  = a1[src] + a2[dst];
        float att = 1.0f / (1.0f + __expf(-av));
        u32 a16 = (u32)lrintf(att * 65535.0f);        // in [0, 65535]
        sorted[base + rk] = (a16 << 16) | (u32)dst;
    }
}

// ---------------------------------------------------------------------------
// Gather (R13-proven): depth-16 MLP over compressed u32 records; runtime
// dtype branch. One wave per src node, lane l = cols 2l,2l+1.
// ---------------------------------------------------------------------------
#define ATTDEC(r) ((float)((r) >> 16) * (1.0f / 65535.0f))

__global__ __launch_bounds__(256) void gather_kernel(
    const int* __restrict__ ptr, const u32* __restrict__ sorted,
    const u32* __restrict__ xjw, const void* __restrict__ x0v,
    void* __restrict__ outv, const int* __restrict__ flags, int n)
{
    const bool bf16 = flags[0] != 0;
    int s = blockIdx.x * 4 + (threadIdx.x >> 6);
    int l = threadIdx.x & 63;
    if (s >= n) return;

    float2 acc0, acc1;
    if (bf16) acc0 = bfpair(((const u32*)x0v)[(size_t)s * 64 + l]);
    else      acc0 = ((const float2*)x0v)[(size_t)s * 64 + l];
    acc1 = make_float2(0.f, 0.f);

    int k = ptr[s], end = ptr[s + 1];

    // main chunks: 16 edges in flight
    while (k + 16 <= end) {
        u32 r[16];
        #pragma unroll
        for (int j = 0; j < 16; ++j) r[j] = sorted[k + j];
        u32 w[16];
        #pragma unroll
        for (int j = 0; j < 16; ++j) w[j] = xjw[(size_t)(r[j] & 0xFFFFu) * 64 + l];
        #pragma unroll
        for (int j = 0; j < 16; ++j) {
            float att = ATTDEC(r[j]);
            float2 xv = bfpair(w[j]);
            if (j & 1) { acc1.x = fmaf(att, xv.x, acc1.x);
                         acc1.y = fmaf(att, xv.y, acc1.y); }
            else       { acc0.x = fmaf(att, xv.x, acc0.x);
                         acc0.y = fmaf(att, xv.y, acc0.y); }
        }
        k += 16;
    }
    if (k + 8 <= end) {
        u32 r[8];
        #pragma unroll
        for (int j = 0; j < 8; ++j) r[j] = sorted[k + j];
        u32 w[8];
        #pragma unroll
        for (int j = 0; j < 8; ++j) w[j] = xjw[(size_t)(r[j] & 0xFFFFu) * 64 + l];
        #pragma unroll
        for (int j = 0; j < 8; ++j) {
            float att = ATTDEC(r[j]);
            float2 xv = bfpair(w[j]);
            if (j & 1) { acc1.x = fmaf(att, xv.x, acc1.x);
                         acc1.y = fmaf(att, xv.y, acc1.y); }
            else       { acc0.x = fmaf(att, xv.x, acc0.x);
                         acc0.y = fmaf(att, xv.y, acc0.y); }
        }
        k += 8;
    }
    if (k + 4 <= end) {
        u32 r[4];
        #pragma unroll
        for (int j = 0; j < 4; ++j) r[j] = sorted[k + j];
        u32 w[4];
        #pragma unroll
        for (int j = 0; j < 4; ++j) w[j] = xjw[(size_t)(r[j] & 0xFFFFu) * 64 + l];
        #pragma unroll
        for (int j = 0; j < 4; ++j) {
            float att = ATTDEC(r[j]);
            float2 xv = bfpair(w[j]);
            if (j & 1) { acc1.x = fmaf(att, xv.x, acc1.x);
                         acc1.y = fmaf(att, xv.y, acc1.y); }
            else       { acc0.x = fmaf(att, xv.x, acc0.x);
                         acc0.y = fmaf(att, xv.y, acc0.y); }
        }
        k += 4;
    }
    for (; k < end; ++k) {
        u32 cur = sorted[k];
        float att = ATTDEC(cur);
        float2 xv = bfpair(xjw[(size_t)(cur & 0xFFFFu) * 64 + l]);
        acc0.x = fmaf(att, xv.x, acc0.x);
        acc0.y = fmaf(att, xv.y, acc0.y);
    }
    acc0.x += acc1.x;
    acc0.y += acc1.y;

    if (bf16) ((u32*)outv)[(size_t)s * 64 + l] = packbf(acc0.x, acc0.y);
    else      ((float2*)outv)[(size_t)s * 64 + l] = acc0;
}

extern "C" void kernel_launch(void* const* d_in, const int* in_sizes, int n_in,
                              void* d_out, int out_size, void* d_ws, size_t ws_size,
                              hipStream_t stream)
{
    const void* x0  = d_in[0];
    /* d_in[1] = x1: unused by the reference computation */
    const int*  ei  = (const int*)d_in[2];
    const void* W1  = d_in[3];
    const void* b1  = d_in[4];
    const void* W2  = d_in[5];
    const void* b2  = d_in[6];
    const void* a1w = d_in[7];
    const void* a1b = d_in[8];
    const void* a2w = d_in[9];
    const void* a2b = d_in[10];

    const int n = in_sizes[0] / DIM;        // 50000 (< 65536: u16 node ids)
    const int e = in_sizes[2] / 2;          // 800000
    const int nblk = (e + CHUNK - 1) / CHUNK;   // 391 (<= 512 for scan1)

    // ws: flags | xj | a1 | a2 | keys0 | keys1 | cnt | off | tot | base |
    //     ptr | sorted(u32)
    char* ws = (char*)d_ws;
    int* flags = (int*)ws;
    size_t off = 1024;
    u16* xj = (u16*)(ws + off);
    off += (size_t)n * DIM * sizeof(u16);   off = (off + 255) & ~(size_t)255;
    float* a1 = (float*)(ws + off);
    off += (size_t)n * sizeof(float);       off = (off + 255) & ~(size_t)255;
    float* a2 = (float*)(ws + off);
    off += (size_t)n * sizeof(float);       off = (off + 255) & ~(size_t)255;
    u32* keys0 = (u32*)(ws + off);
    off += (size_t)e * sizeof(u32);         off = (off + 255) & ~(size_t)255;
    u32* keys1 = (u32*)(ws + off);
    off += (size_t)e * sizeof(u32);         off = (off + 255) & ~(size_t)255;
    int* cntH = (int*)(ws + off);
    off += (size_t)256 * nblk * sizeof(int); off = (off + 255) & ~(size_t)255;
    int* offH = (int*)(ws + off);
    off += (size_t)256 * nblk * sizeof(int); off = (off + 255) & ~(size_t)255;
    int* totH = (int*)(ws + off);  off += 1024;
    int* baseH = (int*)(ws + off); off += 1024;
    int* ptr = (int*)(ws + off);
    off += (size_t)(n + 1) * sizeof(int);   off = (off + 255) & ~(size_t)255;
    u32* sorted = (u32*)(ws + off);

    sniff_kernel<<<1, 64, 0, stream>>>((const u32*)x0, ei, flags);

    const int nchunk = (n + 31) / 32;       // 1563
    const int bpg = (nchunk + 3) / 4;       // blocks per matrix (391)
    const int nbp = 2 * bpg;                // proj blocks (782)
    // interleave 1 proj : (S-1) countH so every CU hosts a mix
    const int S = 1 + (nblk + nbp - 1) / nbp;   // 2
    const int fgrid = nbp * S;                  // 1564

    proj_count_kernel<<<fgrid, 256, 0, stream>>>(x0, W1, b1, W2, b2, a1w, a1b,
        a2w, a2b, xj, a1, a2, ei, keys0, cntH, flags, n, e, nchunk, bpg, nblk, S);

    // MSD bucket CSR build (atomic-free), R12-proven
    scan1_kernel<<<256, 256, 0, stream>>>(cntH, offH, totH, nblk);
    scan2_kernel<<<1, 256, 0, stream>>>(totH, baseH);
    reorderH_kernel<<<nblk, 256, 0, stream>>>(keys0, keys1, offH, baseH, e, nblk);
    const int nbucket = (n >> 8) + 1;       // 196
    bucket_kernel<<<nbucket, 256, 0, stream>>>(keys1, baseH, totH, a1, a2,
                                               ptr, sorted, n);

    int gblocks = (n + 3) / 4;
    gather_kernel<<<gblocks, 256, 0, stream>>>(ptr, sorted, (const u32*)xj,
                                               x0, d_out, flags, n);
}